// Round 1
// baseline (1200.052 us; speedup 1.0000x reference)
//
#include <hip/hip_runtime.h>
#include <hip/hip_bf16.h>

// GraphAttentionV2: B=8, SL=50, N=128, FIN=128, H=8, FH=32
// One block per (b*SL+s, head): 400*8 = 3200 blocks, 256 threads.
//
// Math exploited: s = exp(score).sum(-1) is a SCALAR S per (b,s,i,h);
// the Linear(1,N)+LayerNorm+softmax row is t_j = S*sa_w[j]+sa_b[j] -> LN -> softmax,
// so the [N,H,N] attention tensor is never materialized; out_s = (sum_j e_j * att_w[f,j]) / Z.

#define NN 128
#define FHH 32
#define NHEAD 8

// LDS layout (floats):
//  sh0   : 0          .. 16384        (persistent h0 tile [128][128])
//  sS    : 16384      .. 16512        (persistent per-row S)
//  X     : 16512      .. 16512+16704  (union region)
//   Phase A: sWl[32][129]=4128 | sWr=4128 | sq[128][33]=4224 | sk=4224   (16704)
//   Phase B: sWv=4128 | sv[128][33]=4224 | satt[32][129]=4128 | sav[32][33]=1056
//            sf1=1056 | sf2=1056 | svec=640                               (16288)
#define SMEM_FLOATS (16512 + 16704)

__global__ __launch_bounds__(256) void gat_kernel(
    const float* __restrict__ h0, const float* __restrict__ adj,
    const float* __restrict__ Wl, const float* __restrict__ Wr, const float* __restrict__ Wv,
    const float* __restrict__ sa_w, const float* __restrict__ sa_b,
    const float* __restrict__ ln_w, const float* __restrict__ ln_b,
    const float* __restrict__ att_w, const float* __restrict__ att_b,
    const float* __restrict__ ff_w1, const float* __restrict__ ff_b1,
    const float* __restrict__ ff_w2, const float* __restrict__ ff_b2,
    const float* __restrict__ rezero, float* __restrict__ out)
{
    const int t   = threadIdx.x;
    const int bid = blockIdx.x;
    const int bs  = bid >> 3;   // 0..399  (b*SL + s)
    const int h   = bid & 7;    // head

    extern __shared__ float smem[];
    float* sh0 = smem;            // 16384
    float* sS  = smem + 16384;    // 128
    float* X   = smem + 16512;
    // phase A aliases
    float* sWl = X;               // 4128
    float* sWr = X + 4128;        // 4128
    float* sq  = X + 8256;        // 4224
    float* sk  = X + 12480;       // 4224
    // phase B aliases
    float* sWv  = X;              // 4128
    float* sv   = X + 4128;       // 4224
    float* satt = X + 8352;       // 4128
    float* sav  = X + 12480;      // 1056
    float* sf1  = X + 13536;      // 1056
    float* sf2  = X + 14592;      // 1056
    float* svec = X + 15648;      // 640

    const float INV_SCALE = 0.0055242717280199026f; // 1/sqrt(FH*H*N) = 1/sqrt(32768)

    // ---- Phase 0: stage h0 tile + Wl/Wr head slices ----
    {
        const float4* h4 = (const float4*)(h0 + (size_t)bs * 16384);
        float4* s4 = (float4*)sh0;
        #pragma unroll
        for (int k = 0; k < 16; ++k) s4[t + k * 256] = h4[t + k * 256];

        const float* wlp = Wl + h * 32 * 128;
        const float* wrp = Wr + h * 32 * 128;
        for (int idx = t; idx < 4096; idx += 256) {
            int r = idx >> 7, c = idx & 127;
            sWl[r * 129 + c] = wlp[idx];
            sWr[r * 129 + c] = wrp[idx];
        }
    }
    __syncthreads();

    // ---- Phase A1: q = h0 @ Wl_h^T ; k = -(h0 @ Wr_h^T) ----
    {
        const int f = t & 31, rg = t >> 5;   // f: out feature, rg: 8 groups of 16 rows
        float aq[16], ak[16];
        #pragma unroll
        for (int ii = 0; ii < 16; ++ii) { aq[ii] = 0.f; ak[ii] = 0.f; }
        for (int c = 0; c < 128; ++c) {
            float wl = sWl[f * 129 + c];
            float wr = sWr[f * 129 + c];
            #pragma unroll
            for (int ii = 0; ii < 16; ++ii) {
                float x = sh0[(rg * 16 + ii) * 128 + c];  // broadcast across 32 lanes
                aq[ii] = fmaf(x, wl, aq[ii]);
                ak[ii] = fmaf(x, wr, ak[ii]);
            }
        }
        #pragma unroll
        for (int ii = 0; ii < 16; ++ii) {
            sq[(rg * 16 + ii) * 33 + f] = aq[ii];
            sk[(rg * 16 + ii) * 33 + f] = -ak[ii];
        }
    }
    __syncthreads();

    // ---- Phase A2: S_i = sum_j unmasked exp(q_i . k_j / scale) ----
    {
        const int i = t >> 1, half = t & 1;
        float qr[32];
        #pragma unroll
        for (int f = 0; f < 32; ++f) qr[f] = sq[i * 33 + f];
        const float* adjrow = adj + (size_t)bs * 16384 + i * 128;
        float Sacc = 0.f;
        for (int jj = 0; jj < 64; ++jj) {
            int j = half * 64 + jj;
            float d = 0.f;
            #pragma unroll
            for (int f = 0; f < 32; ++f) d = fmaf(qr[f], sk[j * 33 + f], d);
            float a = adjrow[j] - ((i == j) ? 1.0f : 0.0f);
            if (a >= 0.1f) Sacc += __expf(d * INV_SCALE);  // masked -> exp(-1e6) == 0
        }
        Sacc += __shfl_xor(Sacc, 1);
        if (half == 0) sS[i] = Sacc;
    }
    __syncthreads();

    // ---- Phase B0: stage Wv slice, att/ff weights, vectors ----
    {
        const float* wvp = Wv + h * 32 * 128;
        for (int idx = t; idx < 4096; idx += 256) {
            int r = idx >> 7, c = idx & 127;
            sWv[r * 129 + c]  = wvp[idx];
            satt[r * 129 + c] = att_w[r * 160 + c];       // att_w[:, :128]
        }
        for (int idx = t; idx < 1024; idx += 256) {
            int r = idx >> 5, c = idx & 31;
            sav[r * 33 + c] = att_w[r * 160 + 128 + c];   // att_w[:, 128:160]
            sf1[r * 33 + c] = ff_w1[idx];
            sf2[r * 33 + c] = ff_w2[idx];
        }
        if (t < 128) {
            svec[t]       = sa_w[t];
            svec[128 + t] = sa_b[t];
            svec[256 + t] = ln_w[t];
            svec[384 + t] = ln_b[t];
        }
        if (t < 32) {
            svec[512 + t] = att_b[t];
            svec[544 + t] = ff_b1[t];
            svec[576 + t] = ff_b2[t];
            svec[608 + t] = rezero[t];
        }
    }
    __syncthreads();

    // ---- Phase B1: v = h0 @ Wv_h^T ----
    {
        const int f = t & 31, rg = t >> 5;
        float av[16];
        #pragma unroll
        for (int ii = 0; ii < 16; ++ii) av[ii] = 0.f;
        for (int c = 0; c < 128; ++c) {
            float wv = sWv[f * 129 + c];
            #pragma unroll
            for (int ii = 0; ii < 16; ++ii)
                av[ii] = fmaf(sh0[(rg * 16 + ii) * 128 + c], wv, av[ii]);
        }
        #pragma unroll
        for (int ii = 0; ii < 16; ++ii) sv[(rg * 16 + ii) * 33 + f] = av[ii];
    }
    __syncthreads();

    // ---- Phase B2: per-row LN+softmax (closed form in S) + att + ff + residual ----
    {
        const int i = t >> 1, half = t & 1;
        const float S = sS[i];
        const float* saw = svec, *sab = svec + 128, *lnw = svec + 256, *lnb = svec + 384;

        // LN stats of t_j = S*w_j + b_j
        float sum = 0.f, sumsq = 0.f;
        for (int jj = 0; jj < 64; ++jj) {
            int j = half * 64 + jj;
            float tj = fmaf(S, saw[j], sab[j]);
            sum += tj; sumsq += tj * tj;
        }
        sum   += __shfl_xor(sum, 1);
        sumsq += __shfl_xor(sumsq, 1);
        float mu   = sum * (1.f / 128.f);
        float var  = sumsq * (1.f / 128.f) - mu * mu;
        float rstd = rsqrtf(var + 1e-5f);

        // softmax-weighted att_w[:, :128] dot (p never materialized)
        float acc[32];
        #pragma unroll
        for (int f = 0; f < 32; ++f) acc[f] = 0.f;
        float Z = 0.f;
        for (int jj = 0; jj < 64; ++jj) {
            int j = half * 64 + jj;
            float tj = fmaf(S, saw[j], sab[j]);
            float y  = (tj - mu) * rstd * lnw[j] + lnb[j];  // bounded by LN -> exp safe
            float e  = __expf(y);
            Z += e;
            #pragma unroll
            for (int f = 0; f < 32; ++f) acc[f] = fmaf(e, satt[f * 129 + j], acc[f]);
        }
        Z += __shfl_xor(Z, 1);
        #pragma unroll
        for (int f = 0; f < 32; ++f) acc[f] += __shfl_xor(acc[f], 1);
        float invZ = 1.0f / Z;

        // sc = p@att_s^T + v@att_v^T + att_b
        float sc[32];
        #pragma unroll
        for (int f = 0; f < 32; ++f) sc[f] = fmaf(acc[f], invZ, svec[512 + f]);
        for (int g = 0; g < 32; ++g) {
            float vg = sv[i * 33 + g];
            #pragma unroll
            for (int f = 0; f < 32; ++f) sc[f] = fmaf(vg, sav[f * 33 + g], sc[f]);
        }

        // ff: leaky(sc@W1^T+b1)@W2^T+b2 ; out = sc + rezero*ff
        float f1[32];
        #pragma unroll
        for (int g = 0; g < 32; ++g) {
            float a = svec[544 + g];
            #pragma unroll
            for (int f = 0; f < 32; ++f) a = fmaf(sc[f], sf1[g * 33 + f], a);
            f1[g] = fmaxf(a, 0.01f * a);
        }
        float o[16];
        #pragma unroll
        for (int fo = 0; fo < 16; ++fo) {
            int f = half * 16 + fo;
            float a = svec[576 + f];
            #pragma unroll
            for (int g = 0; g < 32; ++g) a = fmaf(f1[g], sf2[f * 33 + g], a);
            o[fo] = fmaf(svec[608 + f], a, sc[f]);
        }
        float* op = out + (size_t)(bs * 128 + i) * 256 + h * 32 + half * 16;
        float4* o4 = (float4*)op;
        #pragma unroll
        for (int v4 = 0; v4 < 4; ++v4)
            o4[v4] = make_float4(o[v4 * 4], o[v4 * 4 + 1], o[v4 * 4 + 2], o[v4 * 4 + 3]);
    }
}

extern "C" void kernel_launch(void* const* d_in, const int* in_sizes, int n_in,
                              void* d_out, int out_size, void* d_ws, size_t ws_size,
                              hipStream_t stream) {
    const float* h0    = (const float*)d_in[0];
    const float* adj   = (const float*)d_in[1];
    const float* Wl    = (const float*)d_in[2];
    const float* Wr    = (const float*)d_in[3];
    const float* Wv    = (const float*)d_in[4];
    const float* sa_w  = (const float*)d_in[5];
    const float* sa_b  = (const float*)d_in[6];
    const float* ln_w  = (const float*)d_in[7];
    const float* ln_b  = (const float*)d_in[8];
    const float* att_w = (const float*)d_in[9];
    const float* att_b = (const float*)d_in[10];
    const float* ff_w1 = (const float*)d_in[11];
    const float* ff_b1 = (const float*)d_in[12];
    const float* ff_w2 = (const float*)d_in[13];
    const float* ff_b2 = (const float*)d_in[14];
    const float* rz    = (const float*)d_in[15];
    float* outp = (float*)d_out;

    gat_kernel<<<dim3(3200), dim3(256), SMEM_FLOATS * sizeof(float), stream>>>(
        h0, adj, Wl, Wr, Wv, sa_w, sa_b, ln_w, ln_b,
        att_w, att_b, ff_w1, ff_b1, ff_w2, ff_b2, rz, outp);
}

// Round 2
// 115.217 us; speedup vs baseline: 10.4155x; 10.4155x over previous
//
#include <hip/hip_runtime.h>
#include <hip/hip_bf16.h>

// GraphAttentionV2 (B=8,SL=50,N=128,FIN=128,H=8,FH=32) — MFMA rewrite.
// One block per (bs,h): 3200 blocks x 256 threads (4 waves), 2 blocks/CU.
// All matmuls on v_mfma_f32_16x16x32_bf16; softmax/LN closed-form in the
// scalar S = sum_j exp(q_i.k_j/scale) (attention matrix never materialized).
//
// Fragment layouts (guide §3, m89/m91/m92-verified):
//   A: A[l&15][(l>>4)*8 + r]   (8 contiguous bf16 per lane)
//   B: B[(l>>4)*8+r][l&15] = W[l&15][(l>>4)*8+r] for out = X@W^T (W natural row-major)
//   C: row=(l>>4)*4+reg, col=l&15

typedef __attribute__((ext_vector_type(8))) short bf16x8;
typedef __attribute__((ext_vector_type(4))) float f32x4;

#define MFMA16(a, b, c) __builtin_amdgcn_mfma_f32_16x16x32_bf16(a, b, c, 0, 0, 0)

static __device__ __forceinline__ short f2b(float f) {
    unsigned u = __builtin_bit_cast(unsigned, f);
    return (short)((u + 0x7FFFu + ((u >> 16) & 1u)) >> 16);   // RNE bf16
}

static __device__ __forceinline__ void ld8(const float* p, float* d) {
    float4 x0 = *(const float4*)p;
    float4 x1 = *(const float4*)(p + 4);
    d[0]=x0.x; d[1]=x0.y; d[2]=x0.z; d[3]=x0.w;
    d[4]=x1.x; d[5]=x1.y; d[6]=x1.z; d[7]=x1.w;
}

// LDS layout (bytes): bf16 tiles padded so ds_read_b128 is <=2-way (free).
#define OFF_WL 0        // short[32][136]  Wl_h   -> phase B: Wv_h
#define OFF_WR 8704     // short[32][136]  Wr_h   -> phase B: att_w[:, :128]
#define OFF_Q  17408    // short[128][40]  q      -> phase 5: sc (bf16)
#define OFF_K  27648    // short[128][40]  k      -> phase 6: f1 (bf16)
#define OFF_V  37888    // short[128][40]  v
#define OFF_AV 48128    // short[32][40]   att_w[:,128:]
#define OFF_W1 50688    // short[32][40]   ff_w1
#define OFF_W2 53248    // short[32][40]   ff_w2
#define OFF_F  55808    // float[904]: vA,vB,vL,vlnb,S,Z,bias(4x32),stats
#define SMEM_BYTES (55808 + 904*4)   // 59424

__global__ __launch_bounds__(256, 2) void gat2(
    const float* __restrict__ h0, const float* __restrict__ adj,
    const float* __restrict__ Wl, const float* __restrict__ Wr, const float* __restrict__ Wv,
    const float* __restrict__ sa_w, const float* __restrict__ sa_b,
    const float* __restrict__ ln_w, const float* __restrict__ ln_b,
    const float* __restrict__ att_w, const float* __restrict__ att_b,
    const float* __restrict__ ff_w1, const float* __restrict__ ff_b1,
    const float* __restrict__ ff_w2, const float* __restrict__ ff_b2,
    const float* __restrict__ rezero, float* __restrict__ out)
{
    const int t = threadIdx.x;
    // XCD swizzle: put all 8 heads of one (bs) tile on the same XCD (bid%8).
    const int bid  = blockIdx.x;
    const int slot = bid >> 3;                  // 0..399
    const int bs   = (bid & 7) * 50 + (slot >> 3);
    const int h    = slot & 7;

    const int w  = t >> 6;       // wave 0..3
    const int l  = t & 63;
    const int lo = l & 15;       // A-row / C-col / B-col
    const int hi = l >> 4;       // k-group / C-row-group

    extern __shared__ char smem[];
    short* sWl  = (short*)(smem + OFF_WL);
    short* sWr  = (short*)(smem + OFF_WR);
    short* sq   = (short*)(smem + OFF_Q);
    short* sk   = (short*)(smem + OFF_K);
    short* sv   = (short*)(smem + OFF_V);
    short* satv = (short*)(smem + OFF_AV);
    short* sW1  = (short*)(smem + OFF_W1);
    short* sW2  = (short*)(smem + OFF_W2);
    short* sWv  = sWl;    // phase-B alias
    short* satt = sWr;    // phase-B alias
    short* ssc  = sq;     // phase-5 alias
    short* sf1  = sk;     // phase-6 alias
    float* svA   = (float*)(smem + OFF_F);
    float* svB   = svA + 128;
    float* svL   = svA + 256;
    float* svlnb = svA + 384;
    float* sS    = svA + 512;
    float* sZ    = svA + 640;
    float* sbias = svA + 768;   // [att_b | ff_b1 | ff_b2 | rezero] x32
    float* sStat = svA + 896;   // Mw, Mb, Eww, Ewb, Ebb

    const float INV_SCALE = 0.0055242717280199026f;  // 1/sqrt(32768)
    const f32x4 Z4 = {0.f, 0.f, 0.f, 0.f};

    // ---------------- Phase 0: stage Wl_h, Wr_h (bf16) ----------------
    {
        const float* wl = Wl + h * 4096;
        const float* wr = Wr + h * 4096;
        #pragma unroll
        for (int k = 0; k < 16; ++k) {
            int idx = t + k * 256;
            int r = idx >> 7, c = idx & 127;
            sWl[r * 136 + c] = f2b(wl[idx]);
            sWr[r * 136 + c] = f2b(wr[idx]);
        }
    }
    __syncthreads();

    // ---------------- Phase 1: q = h0@Wl^T, k = -(h0@Wr^T) ----------------
    const float* h0b = h0 + (size_t)bs * 16384;
    #pragma unroll
    for (int mt = 0; mt < 2; ++mt) {
        const float* rp = h0b + (w * 32 + mt * 16 + lo) * 128;
        bf16x8 af[4];
        #pragma unroll
        for (int ks = 0; ks < 4; ++ks) {
            float x[8]; ld8(rp + ks * 32 + hi * 8, x);
            #pragma unroll
            for (int r = 0; r < 8; ++r) af[ks][r] = f2b(x[r]);
        }
        f32x4 cq[2], ck[2];
        cq[0] = Z4; cq[1] = Z4; ck[0] = Z4; ck[1] = Z4;
        #pragma unroll
        for (int ks = 0; ks < 4; ++ks) {
            #pragma unroll
            for (int nt = 0; nt < 2; ++nt) {
                bf16x8 bq = *(const bf16x8*)(sWl + (nt * 16 + lo) * 136 + ks * 32 + hi * 8);
                bf16x8 bk = *(const bf16x8*)(sWr + (nt * 16 + lo) * 136 + ks * 32 + hi * 8);
                cq[nt] = MFMA16(af[ks], bq, cq[nt]);
                ck[nt] = MFMA16(af[ks], bk, ck[nt]);
            }
        }
        #pragma unroll
        for (int nt = 0; nt < 2; ++nt)
            #pragma unroll
            for (int r = 0; r < 4; ++r) {
                int orow = w * 32 + mt * 16 + hi * 4 + r, ocol = nt * 16 + lo;
                sq[orow * 40 + ocol] = f2b(cq[nt][r]);
                sk[orow * 40 + ocol] = f2b(-ck[nt][r]);
            }
    }
    __syncthreads();

    // ---------------- Phase 2: stage phase-B weights + score/S ----------------
    {
        const float* wv = Wv + h * 4096;
        #pragma unroll
        for (int k = 0; k < 16; ++k) {
            int idx = t + k * 256;
            int r = idx >> 7, c = idx & 127;
            sWv[r * 136 + c]  = f2b(wv[idx]);
            satt[r * 136 + c] = f2b(att_w[r * 160 + c]);
        }
        #pragma unroll
        for (int k = 0; k < 4; ++k) {
            int idx = t + k * 256;
            int g = idx >> 5, f = idx & 31;
            satv[g * 40 + f] = f2b(att_w[g * 160 + 128 + f]);  // row g of att_w, tail cols
            sW1[g * 40 + f]  = f2b(ff_w1[idx]);
            sW2[g * 40 + f]  = f2b(ff_w2[idx]);
        }
        if (t < 128) {
            float lw = ln_w[t];
            svA[t]   = lw * sa_w[t];
            svB[t]   = lw * sa_b[t];
            svL[t]   = lw;
            svlnb[t] = ln_b[t];
        } else if (t < 160) {
            int c = t - 128;
            sbias[c]      = att_b[c];
            sbias[32 + c] = ff_b1[c];
            sbias[64 + c] = ff_b2[c];
            sbias[96 + c] = rezero[c];
        }
    }
    {   // score = q@k^T (K=32, one MFMA per 16x16 tile), mask+exp -> S per row
        bf16x8 aq[2];
        #pragma unroll
        for (int mt = 0; mt < 2; ++mt)
            aq[mt] = *(const bf16x8*)(sq + (w * 32 + mt * 16 + lo) * 40 + hi * 8);
        float Sp[8];
        #pragma unroll
        for (int r = 0; r < 8; ++r) Sp[r] = 0.f;
        const float* adjb = adj + (size_t)bs * 16384;
        #pragma unroll 2
        for (int nt = 0; nt < 8; ++nt) {
            bf16x8 bk = *(const bf16x8*)(sk + (nt * 16 + lo) * 40 + hi * 8);
            int j = nt * 16 + lo;
            #pragma unroll
            for (int mt = 0; mt < 2; ++mt) {
                f32x4 c = MFMA16(aq[mt], bk, Z4);
                const float* ap = adjb + (w * 32 + mt * 16 + hi * 4) * 128 + j;
                #pragma unroll
                for (int r = 0; r < 4; ++r) {
                    int i = w * 32 + mt * 16 + hi * 4 + r;
                    float am = ap[r * 128] - ((i == j) ? 1.0f : 0.0f);
                    if (am >= 0.1f) Sp[mt * 4 + r] += __expf(c[r] * INV_SCALE);
                }
            }
        }
        #pragma unroll
        for (int m = 1; m <= 8; m <<= 1)
            #pragma unroll
            for (int r = 0; r < 8; ++r) Sp[r] += __shfl_xor(Sp[r], m);
        if (lo == 0)
            #pragma unroll
            for (int mt = 0; mt < 2; ++mt)
                #pragma unroll
                for (int r = 0; r < 4; ++r)
                    sS[w * 32 + mt * 16 + hi * 4 + r] = Sp[mt * 4 + r];
    }
    __syncthreads();

    // ---------------- Phase 3: v = h0@Wv^T  + LN input-global stats ----------------
    #pragma unroll
    for (int mt = 0; mt < 2; ++mt) {
        const float* rp = h0b + (w * 32 + mt * 16 + lo) * 128;
        bf16x8 af[4];
        #pragma unroll
        for (int ks = 0; ks < 4; ++ks) {
            float x[8]; ld8(rp + ks * 32 + hi * 8, x);
            #pragma unroll
            for (int r = 0; r < 8; ++r) af[ks][r] = f2b(x[r]);
        }
        f32x4 cv[2]; cv[0] = Z4; cv[1] = Z4;
        #pragma unroll
        for (int ks = 0; ks < 4; ++ks)
            #pragma unroll
            for (int nt = 0; nt < 2; ++nt) {
                bf16x8 bv = *(const bf16x8*)(sWv + (nt * 16 + lo) * 136 + ks * 32 + hi * 8);
                cv[nt] = MFMA16(af[ks], bv, cv[nt]);
            }
        #pragma unroll
        for (int nt = 0; nt < 2; ++nt)
            #pragma unroll
            for (int r = 0; r < 4; ++r)
                sv[(w * 32 + mt * 16 + hi * 4 + r) * 40 + nt * 16 + lo] = f2b(cv[nt][r]);
    }
    if (t < 64) {   // wave 0: 5 scalar stats of sa_w/sa_b
        float w0 = sa_w[t], b0 = sa_b[t], w1 = sa_w[t + 64], b1 = sa_b[t + 64];
        float sw = w0 + w1, sb = b0 + b1;
        float sww = w0 * w0 + w1 * w1, swb = w0 * b0 + w1 * b1, sbb = b0 * b0 + b1 * b1;
        #pragma unroll
        for (int m = 1; m <= 32; m <<= 1) {
            sw += __shfl_xor(sw, m); sb += __shfl_xor(sb, m); sww += __shfl_xor(sww, m);
            swb += __shfl_xor(swb, m); sbb += __shfl_xor(sbb, m);
        }
        if (t == 0) {
            const float inv = 1.0f / 128.0f;
            sStat[0] = sw * inv; sStat[1] = sb * inv; sStat[2] = sww * inv;
            sStat[3] = swb * inv; sStat[4] = sbb * inv;
        }
    }
    __syncthreads();

    // ---------------- Phase 4: E = exp(LN row) -> C1 = E@att_s^T, C2 = v@att_v^T, Z ----------------
    f32x4 C1[2][2], C2[2][2];
    {
        const float Mw = sStat[0], Mb = sStat[1], Eww = sStat[2], Ewb = sStat[3], Ebb = sStat[4];
        #pragma unroll
        for (int mt = 0; mt < 2; ++mt) {
            int row = w * 32 + mt * 16 + lo;
            float S   = sS[row];
            float mu  = S * Mw + Mb;
            float Et2 = S * S * Eww + 2.f * S * Ewb + Ebb;
            float rstd = rsqrtf((Et2 - mu * mu) + 1e-5f);
            float c1 = rstd * S, c2 = rstd, c3 = -rstd * mu;
            float Zp = 0.f;
            C1[mt][0] = Z4; C1[mt][1] = Z4;
            #pragma unroll
            for (int ks = 0; ks < 4; ++ks) {
                int jb = ks * 32 + hi * 8;
                float A8[8], B8[8], L8[8], N8[8];
                ld8(svA + jb, A8); ld8(svB + jb, B8); ld8(svL + jb, L8); ld8(svlnb + jb, N8);
                bf16x8 ea;
                #pragma unroll
                for (int r = 0; r < 8; ++r) {
                    float y = c1 * A8[r] + c2 * B8[r] + c3 * L8[r] + N8[r];
                    float e = __expf(y);
                    Zp += e;
                    ea[r] = f2b(e);
                }
                #pragma unroll
                for (int nt = 0; nt < 2; ++nt) {
                    bf16x8 bb = *(const bf16x8*)(satt + (nt * 16 + lo) * 136 + jb);
                    C1[mt][nt] = MFMA16(ea, bb, C1[mt][nt]);
                }
            }
            bf16x8 av = *(const bf16x8*)(sv + row * 40 + hi * 8);
            #pragma unroll
            for (int nt = 0; nt < 2; ++nt) {
                bf16x8 bv = *(const bf16x8*)(satv + (nt * 16 + lo) * 40 + hi * 8);
                C2[mt][nt] = MFMA16(av, bv, Z4);
            }
            Zp += __shfl_xor(Zp, 16);
            Zp += __shfl_xor(Zp, 32);
            if (hi == 0) sZ[row] = Zp;
        }
    }
    __syncthreads();

    // sc = C1/Z + C2 + att_b  (keep fp32 in C1; bf16 copy to LDS for FF)
    #pragma unroll
    for (int mt = 0; mt < 2; ++mt)
        #pragma unroll
        for (int r = 0; r < 4; ++r) {
            int i = w * 32 + mt * 16 + hi * 4 + r;
            float invZ = 1.0f / sZ[i];
            #pragma unroll
            for (int nt = 0; nt < 2; ++nt) {
                int col = nt * 16 + lo;
                float sc = C1[mt][nt][r] * invZ + C2[mt][nt][r] + sbias[col];
                C1[mt][nt][r] = sc;
                ssc[i * 40 + col] = f2b(sc);
            }
        }
    __syncthreads();

    // ---------------- Phase 5: f1 = leaky(sc@W1^T + b1) ----------------
    #pragma unroll
    for (int mt = 0; mt < 2; ++mt) {
        bf16x8 as_ = *(const bf16x8*)(ssc + (w * 32 + mt * 16 + lo) * 40 + hi * 8);
        #pragma unroll
        for (int nt = 0; nt < 2; ++nt) {
            bf16x8 b1 = *(const bf16x8*)(sW1 + (nt * 16 + lo) * 40 + hi * 8);
            f32x4 f1 = MFMA16(as_, b1, Z4);
            #pragma unroll
            for (int r = 0; r < 4; ++r) {
                int i = w * 32 + mt * 16 + hi * 4 + r, col = nt * 16 + lo;
                float a = f1[r] + sbias[32 + col];
                sf1[i * 40 + col] = f2b(fmaxf(a, 0.01f * a));
            }
        }
    }
    __syncthreads();

    // ---------------- Phase 6: out = sc + rezero*(f1@W2^T + b2) ----------------
    {
        float* outb = out + (size_t)bs * 32768 + h * 32;
        #pragma unroll
        for (int mt = 0; mt < 2; ++mt) {
            bf16x8 af1 = *(const bf16x8*)(sf1 + (w * 32 + mt * 16 + lo) * 40 + hi * 8);
            #pragma unroll
            for (int nt = 0; nt < 2; ++nt) {
                bf16x8 b2 = *(const bf16x8*)(sW2 + (nt * 16 + lo) * 40 + hi * 8);
                f32x4 f2 = MFMA16(af1, b2, Z4);
                #pragma unroll
                for (int r = 0; r < 4; ++r) {
                    int i = w * 32 + mt * 16 + hi * 4 + r, col = nt * 16 + lo;
                    outb[i * 256 + col] = C1[mt][nt][r] + sbias[96 + col] * (f2[r] + sbias[64 + col]);
                }
            }
        }
    }
}

extern "C" void kernel_launch(void* const* d_in, const int* in_sizes, int n_in,
                              void* d_out, int out_size, void* d_ws, size_t ws_size,
                              hipStream_t stream) {
    const float* h0    = (const float*)d_in[0];
    const float* adj   = (const float*)d_in[1];
    const float* Wl    = (const float*)d_in[2];
    const float* Wr    = (const float*)d_in[3];
    const float* Wv    = (const float*)d_in[4];
    const float* sa_w  = (const float*)d_in[5];
    const float* sa_b  = (const float*)d_in[6];
    const float* ln_w  = (const float*)d_in[7];
    const float* ln_b  = (const float*)d_in[8];
    const float* att_w = (const float*)d_in[9];
    const float* att_b = (const float*)d_in[10];
    const float* ff_w1 = (const float*)d_in[11];
    const float* ff_b1 = (const float*)d_in[12];
    const float* ff_w2 = (const float*)d_in[13];
    const float* ff_b2 = (const float*)d_in[14];
    const float* rz    = (const float*)d_in[15];
    float* outp = (float*)d_out;

    gat2<<<dim3(3200), dim3(256), SMEM_BYTES, stream>>>(
        h0, adj, Wl, Wr, Wv, sa_w, sa_b, ln_w, ln_b,
        att_w, att_b, ff_w1, ff_b1, ff_w2, ff_b2, rz, outp);
}